// Round 1
// baseline (750.297 us; speedup 1.0000x reference)
//
#include <hip/hip_runtime.h>

#define NN 50000
#define DD 256
#define OUTD 256
#define RK 8
#define CAPA 64
#define CAPD 16
#define SCALING 2.0f
#define GR 16

typedef unsigned int u32;

// ---------------------------------------------------------------------------
// Build per-row edge lists (slot = atomicAdd on row counter). Overflow edges
// (essentially never: degrees ~Poisson(16) with cap 64) fall back to direct
// f32 atomic scatter so the result is always correct.
// ---------------------------------------------------------------------------
__global__ __launch_bounds__(256) void k_build(
    const int* __restrict__ erow, const int* __restrict__ ecol,
    const float* __restrict__ eval, int ne, int cap,
    int* __restrict__ cnt, uint2* __restrict__ list,
    const float* __restrict__ feat, const float* __restrict__ dfeat,
    float* acc0 /*adjF*/, float* acc1 /*Fin*/, int isDelta)
{
    int e = blockIdx.x * 256 + threadIdx.x;
    if (e >= ne) return;
    int r = erow[e];
    int c = ecol[e];
    float v = eval[e];
    int slot = atomicAdd(cnt + r, 1);
    if (slot < cap) {
        list[(size_t)r * cap + slot] = make_uint2((u32)c, __float_as_uint(v));
    } else {
        const float* f  = feat  + (size_t)c * DD;
        const float* df = dfeat + (size_t)c * DD;
        float* a0 = acc0 + (size_t)r * DD;
        float* a1 = acc1 + (size_t)r * DD;
        if (isDelta) {
            for (int i = 0; i < DD; ++i) atomicAdd(a1 + i, v * (f[i] + df[i]));
        } else {
            for (int i = 0; i < DD; ++i) {
                atomicAdd(a0 + i, v * f[i]);
                atomicAdd(a1 + i, v * df[i]);
            }
        }
    }
}

// ---------------------------------------------------------------------------
// Wave-per-row pull SpMM: accumulate adj@F -> accAdjF, adj@dF + dadj@(F+dF)
// -> accFin, entirely in registers; one vectorized RMW per row (adds on top
// of any fallback-atomic contributions already in the zeroed accumulators).
// ---------------------------------------------------------------------------
__global__ __launch_bounds__(256) void k_spmm(
    const int* __restrict__ cntA, const uint2* __restrict__ listA,
    const int* __restrict__ cntD, const uint2* __restrict__ listD,
    const float* __restrict__ feat, const float* __restrict__ dfeat,
    float* accAdjF, float* accFin)
{
    int wid  = (int)((blockIdx.x * 256 + threadIdx.x) >> 6);
    int lane = threadIdx.x & 63;
    if (wid >= NN) return;
    int degA = min(cntA[wid], CAPA);
    int degD = min(cntD[wid], CAPD);
    uint2 myA = listA[(size_t)wid * CAPA + lane];
    uint2 myD = make_uint2(0u, 0u);
    if (lane < CAPD) myD = listD[(size_t)wid * CAPD + lane];

    float4 aF = make_float4(0.f, 0.f, 0.f, 0.f);
    float4 aD = make_float4(0.f, 0.f, 0.f, 0.f);

    for (int e = 0; e < degA; ++e) {
        int   c = __shfl((int)myA.x, e);
        float v = __shfl(__uint_as_float(myA.y), e);
        float4 f  = ((const float4*)(feat  + (size_t)c * DD))[lane];
        float4 df = ((const float4*)(dfeat + (size_t)c * DD))[lane];
        aF.x = fmaf(v, f.x, aF.x);  aF.y = fmaf(v, f.y, aF.y);
        aF.z = fmaf(v, f.z, aF.z);  aF.w = fmaf(v, f.w, aF.w);
        aD.x = fmaf(v, df.x, aD.x); aD.y = fmaf(v, df.y, aD.y);
        aD.z = fmaf(v, df.z, aD.z); aD.w = fmaf(v, df.w, aD.w);
    }
    for (int e = 0; e < degD; ++e) {
        int   c = __shfl((int)myD.x, e);
        float v = __shfl(__uint_as_float(myD.y), e);
        float4 f  = ((const float4*)(feat  + (size_t)c * DD))[lane];
        float4 df = ((const float4*)(dfeat + (size_t)c * DD))[lane];
        aD.x = fmaf(v, f.x + df.x, aD.x); aD.y = fmaf(v, f.y + df.y, aD.y);
        aD.z = fmaf(v, f.z + df.z, aD.z); aD.w = fmaf(v, f.w + df.w, aD.w);
    }

    float4* p0 = (float4*)(accAdjF + (size_t)wid * DD) + lane;
    float4 t0 = *p0;
    t0.x += aF.x; t0.y += aF.y; t0.z += aF.z; t0.w += aF.w;
    *p0 = t0;
    float4* p1 = (float4*)(accFin + (size_t)wid * DD) + lane;
    float4 t1 = *p1;
    t1.x += aD.x; t1.y += aD.y; t1.z += aD.z; t1.w += aD.w;
    *p1 = t1;
}

// ---------------------------------------------------------------------------
// Fallback direct-atomic scatter (used only when ws is too small for lists).
// ---------------------------------------------------------------------------
__global__ __launch_bounds__(256) void k_scatter_adj(
    const int* __restrict__ erow, const int* __restrict__ ecol,
    const float* __restrict__ eval, int ne,
    const float* __restrict__ feat, const float* __restrict__ dfeat,
    float* accAdjF, float* accFin)
{
    int e    = (int)((blockIdx.x * 256 + threadIdx.x) >> 6);
    int lane = threadIdx.x & 63;
    if (e >= ne) return;
    int r = erow[e]; int c = ecol[e]; float v = eval[e];
    float4 f  = ((const float4*)(feat  + (size_t)c * DD))[lane];
    float4 df = ((const float4*)(dfeat + (size_t)c * DD))[lane];
    float* pA = accAdjF + (size_t)r * DD + lane * 4;
    atomicAdd(pA + 0, v * f.x); atomicAdd(pA + 1, v * f.y);
    atomicAdd(pA + 2, v * f.z); atomicAdd(pA + 3, v * f.w);
    float* pF = accFin + (size_t)r * DD + lane * 4;
    atomicAdd(pF + 0, v * df.x); atomicAdd(pF + 1, v * df.y);
    atomicAdd(pF + 2, v * df.z); atomicAdd(pF + 3, v * df.w);
}

__global__ __launch_bounds__(256) void k_scatter_delta(
    const int* __restrict__ erow, const int* __restrict__ ecol,
    const float* __restrict__ eval, int ne,
    const float* __restrict__ feat, const float* __restrict__ dfeat,
    float* accFin)
{
    int e    = (int)((blockIdx.x * 256 + threadIdx.x) >> 6);
    int lane = threadIdx.x & 63;
    if (e >= ne) return;
    int r = erow[e]; int c = ecol[e]; float v = eval[e];
    float4 f  = ((const float4*)(feat  + (size_t)c * DD))[lane];
    float4 df = ((const float4*)(dfeat + (size_t)c * DD))[lane];
    float* pF = accFin + (size_t)r * DD + lane * 4;
    atomicAdd(pF + 0, v * (f.x + df.x)); atomicAdd(pF + 1, v * (f.y + df.y));
    atomicAdd(pF + 2, v * (f.z + df.z)); atomicAdd(pF + 3, v * (f.w + df.w));
}

// ---------------------------------------------------------------------------
// B = F_input + adj@F (in place over the adj@F accumulator = d_out B region),
// plus BA = B @ lora_A  (rank 8) via in-wave butterfly reduction.
// ---------------------------------------------------------------------------
__global__ __launch_bounds__(256) void k_bba(
    const float* __restrict__ accFin, float* bio,
    const float* __restrict__ loraA, float* __restrict__ BA)
{
    int wid  = (int)((blockIdx.x * 256 + threadIdx.x) >> 6);
    int lane = threadIdx.x & 63;
    if (wid >= NN) return;
    float4 fin = ((const float4*)(accFin + (size_t)wid * DD))[lane];
    float4* pb = (float4*)(bio + (size_t)wid * DD) + lane;
    float4 b = *pb;
    b.x += fin.x; b.y += fin.y; b.z += fin.z; b.w += fin.w;
    *pb = b;

    int j0 = lane * 4;
    float pa[RK];
#pragma unroll
    for (int p = 0; p < RK; ++p) {
        pa[p] = b.x * loraA[(size_t)(j0 + 0) * RK + p]
              + b.y * loraA[(size_t)(j0 + 1) * RK + p]
              + b.z * loraA[(size_t)(j0 + 2) * RK + p]
              + b.w * loraA[(size_t)(j0 + 3) * RK + p];
    }
#pragma unroll
    for (int off = 32; off; off >>= 1) {
#pragma unroll
        for (int p = 0; p < RK; ++p) pa[p] += __shfl_xor(pa[p], off);
    }
    if (lane == 0) {
#pragma unroll
        for (int p = 0; p < RK; ++p) BA[(size_t)wid * RK + p] = pa[p];
    }
}

// ---------------------------------------------------------------------------
// Fused GEMM: fixed_term = F_input @ W (in place over F_input region, staged
// through LDS first) and new_Z = fixed_term + (BA @ lora_B) * SCALING.
// 128 threads, 16 rows x 256 cols per block, 2 cols/thread.
// ---------------------------------------------------------------------------
__global__ __launch_bounds__(128) void k_gemm(
    float* finIO,                    // in: F_input, out: fixed_term
    const float* __restrict__ W,     // [DD][OUTD]
    const float* __restrict__ BA,    // [NN][RK]
    const float* __restrict__ loraB, // [RK][OUTD]
    float* __restrict__ zOut)        // [NN][OUTD]
{
    __shared__ float fin[GR][DD + 4];
    __shared__ float lb[RK][OUTD];
    __shared__ float ba[GR][RK];
    int t = threadIdx.x;
    int row0 = blockIdx.x * GR;

#pragma unroll
    for (int i = 0; i < 8; ++i) {
        int idx = i * 128 + t;
        int r = idx >> 6, p = idx & 63;
        float4 v = ((const float4*)(finIO + (size_t)(row0 + r) * DD))[p];
        *(float4*)&fin[r][p * 4] = v;
    }
#pragma unroll
    for (int i = 0; i < 16; ++i) {
        int idx = i * 128 + t;
        lb[idx >> 8][idx & 255] = loraB[idx] * SCALING;
    }
    ba[t >> 3][t & 7] = BA[(size_t)row0 * RK + t];
    __syncthreads();

    int c0 = t, c1 = t + 128;
    float acc0[GR], acc1[GR];
#pragma unroll
    for (int r = 0; r < GR; ++r) { acc0[r] = 0.f; acc1[r] = 0.f; }

    for (int k = 0; k < DD; k += 4) {
        const float* wk = W + (size_t)k * OUTD;
        float w00 = wk[c0], w01 = wk[OUTD + c0], w02 = wk[2 * OUTD + c0], w03 = wk[3 * OUTD + c0];
        float w10 = wk[c1], w11 = wk[OUTD + c1], w12 = wk[2 * OUTD + c1], w13 = wk[3 * OUTD + c1];
#pragma unroll
        for (int r = 0; r < GR; ++r) {
            float4 f = *(const float4*)&fin[r][k];
            acc0[r] += f.x * w00 + f.y * w01 + f.z * w02 + f.w * w03;
            acc1[r] += f.x * w10 + f.y * w11 + f.z * w12 + f.w * w13;
        }
    }

#pragma unroll
    for (int r = 0; r < GR; ++r) {
        float z0 = acc0[r], z1 = acc1[r];
#pragma unroll
        for (int p = 0; p < RK; ++p) {
            float bv = ba[r][p];
            z0 = fmaf(bv, lb[p][c0], z0);
            z1 = fmaf(bv, lb[p][c1], z1);
        }
        size_t off = (size_t)(row0 + r) * OUTD;
        finIO[off + c0] = acc0[r];
        finIO[off + c1] = acc1[r];
        zOut[off + c0]  = z0;
        zOut[off + c1]  = z1;
    }
}

// ---------------------------------------------------------------------------
extern "C" void kernel_launch(void* const* d_in, const int* in_sizes, int n_in,
                              void* d_out, int out_size, void* d_ws, size_t ws_size,
                              hipStream_t stream)
{
    const float* feat  = (const float*)d_in[0];
    const float* dfeat = (const float*)d_in[1];
    const int*   arow  = (const int*)d_in[2];
    const int*   acol  = (const int*)d_in[3];
    const float* aval  = (const float*)d_in[4];
    const int*   drow  = (const int*)d_in[5];
    const int*   dcol  = (const int*)d_in[6];
    const float* dval  = (const float*)d_in[7];
    const float* W     = (const float*)d_in[8];
    const float* loraA = (const float*)d_in[10];
    const float* loraB = (const float*)d_in[11];
    int E  = in_sizes[2];
    int ED = in_sizes[5];

    float* out    = (float*)d_out;
    float* newZ   = out;                           // region 0
    float* fixedR = out + (size_t)NN * OUTD;       // region 1: F_input acc -> fixed_term
    float* Breg   = out + 2 * (size_t)NN * OUTD;   // region 2: adj@F acc -> B

    char* wsb = (char*)d_ws;
    size_t oListA = 2 * (size_t)NN * 4;                  // after cntA, cntD
    size_t oListD = oListA + (size_t)NN * CAPA * 8;
    size_t oBA    = oListD + (size_t)NN * CAPD * 8;
    size_t need   = oBA + (size_t)NN * RK * 4;

    int*   cntA  = (int*)wsb;
    int*   cntD  = cntA + NN;
    uint2* listA = (uint2*)(wsb + oListA);
    uint2* listD = (uint2*)(wsb + oListD);
    bool useList = (ws_size >= need);
    float* BA    = useList ? (float*)(wsb + oBA) : (float*)wsb;

    // zero accumulators (F_input in fixed region, adj@F in B region)
    hipMemsetAsync(fixedR, 0, (size_t)NN * DD * 4, stream);
    hipMemsetAsync(Breg,   0, (size_t)NN * DD * 4, stream);

    if (useList) {
        hipMemsetAsync(cntA, 0, 2 * (size_t)NN * 4, stream);
        k_build<<<(E + 255) / 256, 256, 0, stream>>>(
            arow, acol, aval, E, CAPA, cntA, listA, feat, dfeat, Breg, fixedR, 0);
        k_build<<<(ED + 255) / 256, 256, 0, stream>>>(
            drow, dcol, dval, ED, CAPD, cntD, listD, feat, dfeat, Breg, fixedR, 1);
        k_spmm<<<(NN * 64 + 255) / 256, 256, 0, stream>>>(
            cntA, listA, cntD, listD, feat, dfeat, Breg, fixedR);
    } else {
        k_scatter_adj<<<(E * 64 + 255) / 256, 256, 0, stream>>>(
            arow, acol, aval, E, feat, dfeat, Breg, fixedR);
        k_scatter_delta<<<(ED * 64 + 255) / 256, 256, 0, stream>>>(
            drow, dcol, dval, ED, feat, dfeat, fixedR);
    }

    k_bba<<<(NN * 64 + 255) / 256, 256, 0, stream>>>(fixedR, Breg, loraA, BA);
    k_gemm<<<NN / GR, 128, 0, stream>>>(fixedR, W, BA, loraB, newZ);
}

// Round 3
// 583.353 us; speedup vs baseline: 1.2862x; 1.2862x over previous
//
#include <hip/hip_runtime.h>

#define NN 50000
#define DD 256
#define OUTD 256
#define RK 8
#define CAPA 64
#define CAPD 16
#define SCALING 2.0f
#define GR 16

typedef unsigned int u32;

__device__ __forceinline__ u32 pack_bf16pair(float lo, float hi) {
    u32 a = __float_as_uint(lo);
    u32 b = __float_as_uint(hi);
    u32 al = (a + 0x7fffu + ((a >> 16) & 1u)) >> 16;          // rne bf16 of lo
    u32 bh = (b + 0x7fffu + ((b >> 16) & 1u)) & 0xffff0000u;  // rne bf16 of hi, in place
    return al | bh;
}

// ---------------------------------------------------------------------------
// Pack (bf16(feat), bf16(dfeat)) into one u32 per element: halves gather bytes
// and merges the two gather streams into one.
// ---------------------------------------------------------------------------
__global__ __launch_bounds__(256) void k_pack(
    const float4* __restrict__ f, const float4* __restrict__ df,
    uint4* __restrict__ p, int n4)
{
    int i = blockIdx.x * 256 + threadIdx.x;
    if (i >= n4) return;
    float4 a = f[i], b = df[i];
    uint4 o;
    o.x = pack_bf16pair(a.x, b.x);
    o.y = pack_bf16pair(a.y, b.y);
    o.z = pack_bf16pair(a.z, b.z);
    o.w = pack_bf16pair(a.w, b.w);
    p[i] = o;
}

// ---------------------------------------------------------------------------
// Build per-row edge lists; overflow (slot >= cap) goes to an overflow list
// consumed by k_fixup after k_spmm2 (keeps the hot path store-only, no RMW).
// ---------------------------------------------------------------------------
__global__ __launch_bounds__(256) void k_build2(
    const int* __restrict__ erow, const int* __restrict__ ecol,
    const float* __restrict__ eval, int ne, int cap,
    int* __restrict__ cnt, uint2* __restrict__ list,
    int* __restrict__ ovfCnt, int4* __restrict__ ovf, int ovfCap, int isDelta)
{
    int e = blockIdx.x * 256 + threadIdx.x;
    if (e >= ne) return;
    int r = erow[e];
    int c = ecol[e];
    float v = eval[e];
    int slot = atomicAdd(cnt + r, 1);
    if (slot < cap) {
        list[(size_t)r * cap + slot] = make_uint2((u32)c, __float_as_uint(v));
    } else {
        int o = atomicAdd(ovfCnt, 1);
        if (o < ovfCap) ovf[o] = make_int4(r, c, __float_as_int(v), isDelta);
    }
}

// ---------------------------------------------------------------------------
// Wave-per-row pull SpMM on packed bf16 pairs. Fuses:
//   Fin  = adj@dF + dadj@(F+dF)      (plain store)
//   B    = adj@F + Fin               (plain store)
//   BA   = B @ lora_A                (butterfly reduce, rank 8)
// ---------------------------------------------------------------------------
__global__ __launch_bounds__(256) void k_spmm2(
    const int* __restrict__ cntA, const uint2* __restrict__ listA,
    const int* __restrict__ cntD, const uint2* __restrict__ listD,
    const uint4* __restrict__ packed,
    float* __restrict__ Fin, float* __restrict__ Bout,
    const float* __restrict__ loraA, float* __restrict__ BA)
{
    int wid  = (int)((blockIdx.x * 256 + threadIdx.x) >> 6);
    int lane = threadIdx.x & 63;
    if (wid >= NN) return;
    int degA = min(cntA[wid], CAPA);
    int degD = min(cntD[wid], CAPD);
    uint2 myA = listA[(size_t)wid * CAPA + lane];
    uint2 myD = make_uint2(0u, 0u);
    if (lane < CAPD) myD = listD[(size_t)wid * CAPD + lane];

    float4 aF = make_float4(0.f, 0.f, 0.f, 0.f);
    float4 aD = make_float4(0.f, 0.f, 0.f, 0.f);

    for (int e = 0; e < degA; ++e) {
        int   c = __shfl((int)myA.x, e);
        float v = __shfl(__uint_as_float(myA.y), e);
        uint4 w = packed[(size_t)c * 64 + lane];
        float f0 = __uint_as_float(w.x << 16), d0 = __uint_as_float(w.x & 0xffff0000u);
        float f1 = __uint_as_float(w.y << 16), d1 = __uint_as_float(w.y & 0xffff0000u);
        float f2 = __uint_as_float(w.z << 16), d2 = __uint_as_float(w.z & 0xffff0000u);
        float f3 = __uint_as_float(w.w << 16), d3 = __uint_as_float(w.w & 0xffff0000u);
        aF.x = fmaf(v, f0, aF.x); aD.x = fmaf(v, d0, aD.x);
        aF.y = fmaf(v, f1, aF.y); aD.y = fmaf(v, d1, aD.y);
        aF.z = fmaf(v, f2, aF.z); aD.z = fmaf(v, d2, aD.z);
        aF.w = fmaf(v, f3, aF.w); aD.w = fmaf(v, d3, aD.w);
    }
    for (int e = 0; e < degD; ++e) {
        int   c = __shfl((int)myD.x, e);
        float v = __shfl(__uint_as_float(myD.y), e);
        uint4 w = packed[(size_t)c * 64 + lane];
        float f0 = __uint_as_float(w.x << 16), d0 = __uint_as_float(w.x & 0xffff0000u);
        float f1 = __uint_as_float(w.y << 16), d1 = __uint_as_float(w.y & 0xffff0000u);
        float f2 = __uint_as_float(w.z << 16), d2 = __uint_as_float(w.z & 0xffff0000u);
        float f3 = __uint_as_float(w.w << 16), d3 = __uint_as_float(w.w & 0xffff0000u);
        aD.x = fmaf(v, f0 + d0, aD.x);
        aD.y = fmaf(v, f1 + d1, aD.y);
        aD.z = fmaf(v, f2 + d2, aD.z);
        aD.w = fmaf(v, f3 + d3, aD.w);
    }

    ((float4*)(Fin + (size_t)wid * DD))[lane] = aD;
    float4 b = make_float4(aF.x + aD.x, aF.y + aD.y, aF.z + aD.z, aF.w + aD.w);
    ((float4*)(Bout + (size_t)wid * DD))[lane] = b;

    int j0 = lane * 4;
    float pa[RK];
#pragma unroll
    for (int p = 0; p < RK; ++p) {
        pa[p] = b.x * loraA[(size_t)(j0 + 0) * RK + p]
              + b.y * loraA[(size_t)(j0 + 1) * RK + p]
              + b.z * loraA[(size_t)(j0 + 2) * RK + p]
              + b.w * loraA[(size_t)(j0 + 3) * RK + p];
    }
#pragma unroll
    for (int off = 32; off; off >>= 1) {
#pragma unroll
        for (int p = 0; p < RK; ++p) pa[p] += __shfl_xor(pa[p], off);
    }
    if (lane == 0) {
#pragma unroll
        for (int p = 0; p < RK; ++p) BA[(size_t)wid * RK + p] = pa[p];
    }
}

// ---------------------------------------------------------------------------
// Patch Fin/B/BA for overflow edges (essentially never runs; grid-stride,
// wave per edge, f32 source data, device atomics).
// ---------------------------------------------------------------------------
__global__ __launch_bounds__(256) void k_fixup(
    const int* __restrict__ ovfCnt, const int4* __restrict__ ovf, int ovfCap,
    const float* __restrict__ feat, const float* __restrict__ dfeat,
    float* Fin, float* Bout, const float* __restrict__ loraA, float* BA)
{
    int waveId = (int)((blockIdx.x * 256 + threadIdx.x) >> 6);
    int nWaves = (int)(gridDim.x * 256 / 64);
    int lane = threadIdx.x & 63;
    int n = min(*ovfCnt, ovfCap);
    for (int i = waveId; i < n; i += nWaves) {
        int4 t = ovf[i];
        int r = t.x, c = t.y, isD = t.w;
        float v = __int_as_float(t.z);
        float4 f  = ((const float4*)(feat  + (size_t)c * DD))[lane];
        float4 df = ((const float4*)(dfeat + (size_t)c * DD))[lane];
        float4 dF, dB;
        if (isD) {
            dF = make_float4(v * (f.x + df.x), v * (f.y + df.y), v * (f.z + df.z), v * (f.w + df.w));
            dB = dF;
        } else {
            dF = make_float4(v * df.x, v * df.y, v * df.z, v * df.w);
            dB = make_float4(fmaf(v, f.x, dF.x), fmaf(v, f.y, dF.y), fmaf(v, f.z, dF.z), fmaf(v, f.w, dF.w));
        }
        float* pF = Fin  + (size_t)r * DD + lane * 4;
        float* pB = Bout + (size_t)r * DD + lane * 4;
        atomicAdd(pF + 0, dF.x); atomicAdd(pF + 1, dF.y);
        atomicAdd(pF + 2, dF.z); atomicAdd(pF + 3, dF.w);
        atomicAdd(pB + 0, dB.x); atomicAdd(pB + 1, dB.y);
        atomicAdd(pB + 2, dB.z); atomicAdd(pB + 3, dB.w);
        int j0 = lane * 4;
        float pa[RK];
#pragma unroll
        for (int p = 0; p < RK; ++p) {
            pa[p] = dB.x * loraA[(size_t)(j0 + 0) * RK + p]
                  + dB.y * loraA[(size_t)(j0 + 1) * RK + p]
                  + dB.z * loraA[(size_t)(j0 + 2) * RK + p]
                  + dB.w * loraA[(size_t)(j0 + 3) * RK + p];
        }
#pragma unroll
        for (int off = 32; off; off >>= 1) {
#pragma unroll
            for (int p = 0; p < RK; ++p) pa[p] += __shfl_xor(pa[p], off);
        }
        if (lane == 0) {
#pragma unroll
            for (int p = 0; p < RK; ++p) atomicAdd(BA + (size_t)r * RK + p, pa[p]);
        }
    }
}

// ===========================================================================
// Fallback tier-B kernels (round-1 versions; used only if ws is too small
// for the packed array). Correct in all regimes.
// ===========================================================================
__global__ __launch_bounds__(256) void k_build(
    const int* __restrict__ erow, const int* __restrict__ ecol,
    const float* __restrict__ eval, int ne, int cap,
    int* __restrict__ cnt, uint2* __restrict__ list,
    const float* __restrict__ feat, const float* __restrict__ dfeat,
    float* acc0, float* acc1, int isDelta)
{
    int e = blockIdx.x * 256 + threadIdx.x;
    if (e >= ne) return;
    int r = erow[e];
    int c = ecol[e];
    float v = eval[e];
    int slot = atomicAdd(cnt + r, 1);
    if (slot < cap) {
        list[(size_t)r * cap + slot] = make_uint2((u32)c, __float_as_uint(v));
    } else {
        const float* f  = feat  + (size_t)c * DD;
        const float* df = dfeat + (size_t)c * DD;
        float* a0 = acc0 + (size_t)r * DD;
        float* a1 = acc1 + (size_t)r * DD;
        if (isDelta) {
            for (int i = 0; i < DD; ++i) atomicAdd(a1 + i, v * (f[i] + df[i]));
        } else {
            for (int i = 0; i < DD; ++i) {
                atomicAdd(a0 + i, v * f[i]);
                atomicAdd(a1 + i, v * df[i]);
            }
        }
    }
}

__global__ __launch_bounds__(256) void k_spmm(
    const int* __restrict__ cntA, const uint2* __restrict__ listA,
    const int* __restrict__ cntD, const uint2* __restrict__ listD,
    const float* __restrict__ feat, const float* __restrict__ dfeat,
    float* accAdjF, float* accFin)
{
    int wid  = (int)((blockIdx.x * 256 + threadIdx.x) >> 6);
    int lane = threadIdx.x & 63;
    if (wid >= NN) return;
    int degA = min(cntA[wid], CAPA);
    int degD = min(cntD[wid], CAPD);
    uint2 myA = listA[(size_t)wid * CAPA + lane];
    uint2 myD = make_uint2(0u, 0u);
    if (lane < CAPD) myD = listD[(size_t)wid * CAPD + lane];
    float4 aF = make_float4(0.f, 0.f, 0.f, 0.f);
    float4 aD = make_float4(0.f, 0.f, 0.f, 0.f);
    for (int e = 0; e < degA; ++e) {
        int   c = __shfl((int)myA.x, e);
        float v = __shfl(__uint_as_float(myA.y), e);
        float4 f  = ((const float4*)(feat  + (size_t)c * DD))[lane];
        float4 df = ((const float4*)(dfeat + (size_t)c * DD))[lane];
        aF.x = fmaf(v, f.x, aF.x);  aF.y = fmaf(v, f.y, aF.y);
        aF.z = fmaf(v, f.z, aF.z);  aF.w = fmaf(v, f.w, aF.w);
        aD.x = fmaf(v, df.x, aD.x); aD.y = fmaf(v, df.y, aD.y);
        aD.z = fmaf(v, df.z, aD.z); aD.w = fmaf(v, df.w, aD.w);
    }
    for (int e = 0; e < degD; ++e) {
        int   c = __shfl((int)myD.x, e);
        float v = __shfl(__uint_as_float(myD.y), e);
        float4 f  = ((const float4*)(feat  + (size_t)c * DD))[lane];
        float4 df = ((const float4*)(dfeat + (size_t)c * DD))[lane];
        aD.x = fmaf(v, f.x + df.x, aD.x); aD.y = fmaf(v, f.y + df.y, aD.y);
        aD.z = fmaf(v, f.z + df.z, aD.z); aD.w = fmaf(v, f.w + df.w, aD.w);
    }
    float4* p0 = (float4*)(accAdjF + (size_t)wid * DD) + lane;
    float4 t0 = *p0;
    t0.x += aF.x; t0.y += aF.y; t0.z += aF.z; t0.w += aF.w;
    *p0 = t0;
    float4* p1 = (float4*)(accFin + (size_t)wid * DD) + lane;
    float4 t1 = *p1;
    t1.x += aD.x; t1.y += aD.y; t1.z += aD.z; t1.w += aD.w;
    *p1 = t1;
}

__global__ __launch_bounds__(256) void k_scatter_adj(
    const int* __restrict__ erow, const int* __restrict__ ecol,
    const float* __restrict__ eval, int ne,
    const float* __restrict__ feat, const float* __restrict__ dfeat,
    float* accAdjF, float* accFin)
{
    int e    = (int)((blockIdx.x * 256 + threadIdx.x) >> 6);
    int lane = threadIdx.x & 63;
    if (e >= ne) return;
    int r = erow[e]; int c = ecol[e]; float v = eval[e];
    float4 f  = ((const float4*)(feat  + (size_t)c * DD))[lane];
    float4 df = ((const float4*)(dfeat + (size_t)c * DD))[lane];
    float* pA = accAdjF + (size_t)r * DD + lane * 4;
    atomicAdd(pA + 0, v * f.x); atomicAdd(pA + 1, v * f.y);
    atomicAdd(pA + 2, v * f.z); atomicAdd(pA + 3, v * f.w);
    float* pF = accFin + (size_t)r * DD + lane * 4;
    atomicAdd(pF + 0, v * df.x); atomicAdd(pF + 1, v * df.y);
    atomicAdd(pF + 2, v * df.z); atomicAdd(pF + 3, v * df.w);
}

__global__ __launch_bounds__(256) void k_scatter_delta(
    const int* __restrict__ erow, const int* __restrict__ ecol,
    const float* __restrict__ eval, int ne,
    const float* __restrict__ feat, const float* __restrict__ dfeat,
    float* accFin)
{
    int e    = (int)((blockIdx.x * 256 + threadIdx.x) >> 6);
    int lane = threadIdx.x & 63;
    if (e >= ne) return;
    int r = erow[e]; int c = ecol[e]; float v = eval[e];
    float4 f  = ((const float4*)(feat  + (size_t)c * DD))[lane];
    float4 df = ((const float4*)(dfeat + (size_t)c * DD))[lane];
    float* pF = accFin + (size_t)r * DD + lane * 4;
    atomicAdd(pF + 0, v * (f.x + df.x)); atomicAdd(pF + 1, v * (f.y + df.y));
    atomicAdd(pF + 2, v * (f.z + df.z)); atomicAdd(pF + 3, v * (f.w + df.w));
}

__global__ __launch_bounds__(256) void k_bba(
    const float* __restrict__ accFin, float* bio,
    const float* __restrict__ loraA, float* __restrict__ BA)
{
    int wid  = (int)((blockIdx.x * 256 + threadIdx.x) >> 6);
    int lane = threadIdx.x & 63;
    if (wid >= NN) return;
    float4 fin = ((const float4*)(accFin + (size_t)wid * DD))[lane];
    float4* pb = (float4*)(bio + (size_t)wid * DD) + lane;
    float4 b = *pb;
    b.x += fin.x; b.y += fin.y; b.z += fin.z; b.w += fin.w;
    *pb = b;
    int j0 = lane * 4;
    float pa[RK];
#pragma unroll
    for (int p = 0; p < RK; ++p) {
        pa[p] = b.x * loraA[(size_t)(j0 + 0) * RK + p]
              + b.y * loraA[(size_t)(j0 + 1) * RK + p]
              + b.z * loraA[(size_t)(j0 + 2) * RK + p]
              + b.w * loraA[(size_t)(j0 + 3) * RK + p];
    }
#pragma unroll
    for (int off = 32; off; off >>= 1) {
#pragma unroll
        for (int p = 0; p < RK; ++p) pa[p] += __shfl_xor(pa[p], off);
    }
    if (lane == 0) {
#pragma unroll
        for (int p = 0; p < RK; ++p) BA[(size_t)wid * RK + p] = pa[p];
    }
}

// ---------------------------------------------------------------------------
// Fused GEMM: fixed_term = F_input @ W (in place, staged through LDS) and
// new_Z = fixed_term + (BA @ lora_B) * SCALING.
// ---------------------------------------------------------------------------
__global__ __launch_bounds__(128) void k_gemm(
    float* finIO,
    const float* __restrict__ W,
    const float* __restrict__ BA,
    const float* __restrict__ loraB,
    float* __restrict__ zOut)
{
    __shared__ float fin[GR][DD + 4];
    __shared__ float lb[RK][OUTD];
    __shared__ float ba[GR][RK];
    int t = threadIdx.x;
    int row0 = blockIdx.x * GR;

#pragma unroll
    for (int i = 0; i < 8; ++i) {
        int idx = i * 128 + t;
        int r = idx >> 6, p = idx & 63;
        float4 v = ((const float4*)(finIO + (size_t)(row0 + r) * DD))[p];
        *(float4*)&fin[r][p * 4] = v;
    }
#pragma unroll
    for (int i = 0; i < 16; ++i) {
        int idx = i * 128 + t;
        lb[idx >> 8][idx & 255] = loraB[idx] * SCALING;
    }
    ba[t >> 3][t & 7] = BA[(size_t)row0 * RK + t];
    __syncthreads();

    int c0 = t, c1 = t + 128;
    float acc0[GR], acc1[GR];
#pragma unroll
    for (int r = 0; r < GR; ++r) { acc0[r] = 0.f; acc1[r] = 0.f; }

    for (int k = 0; k < DD; k += 4) {
        const float* wk = W + (size_t)k * OUTD;
        float w00 = wk[c0], w01 = wk[OUTD + c0], w02 = wk[2 * OUTD + c0], w03 = wk[3 * OUTD + c0];
        float w10 = wk[c1], w11 = wk[OUTD + c1], w12 = wk[2 * OUTD + c1], w13 = wk[3 * OUTD + c1];
#pragma unroll
        for (int r = 0; r < GR; ++r) {
            float4 f = *(const float4*)&fin[r][k];
            acc0[r] += f.x * w00 + f.y * w01 + f.z * w02 + f.w * w03;
            acc1[r] += f.x * w10 + f.y * w11 + f.z * w12 + f.w * w13;
        }
    }

#pragma unroll
    for (int r = 0; r < GR; ++r) {
        float z0 = acc0[r], z1 = acc1[r];
#pragma unroll
        for (int p = 0; p < RK; ++p) {
            float bv = ba[r][p];
            z0 = fmaf(bv, lb[p][c0], z0);
            z1 = fmaf(bv, lb[p][c1], z1);
        }
        size_t off = (size_t)(row0 + r) * OUTD;
        finIO[off + c0] = acc0[r];
        finIO[off + c1] = acc1[r];
        zOut[off + c0]  = z0;
        zOut[off + c1]  = z1;
    }
}

// ---------------------------------------------------------------------------
extern "C" void kernel_launch(void* const* d_in, const int* in_sizes, int n_in,
                              void* d_out, int out_size, void* d_ws, size_t ws_size,
                              hipStream_t stream)
{
    const float* feat  = (const float*)d_in[0];
    const float* dfeat = (const float*)d_in[1];
    const int*   arow  = (const int*)d_in[2];
    const int*   acol  = (const int*)d_in[3];
    const float* aval  = (const float*)d_in[4];
    const int*   drow  = (const int*)d_in[5];
    const int*   dcol  = (const int*)d_in[6];
    const float* dval  = (const float*)d_in[7];
    const float* W     = (const float*)d_in[8];
    const float* loraA = (const float*)d_in[10];
    const float* loraB = (const float*)d_in[11];
    int E  = in_sizes[2];
    int ED = in_sizes[5];

    float* out    = (float*)d_out;
    float* newZ   = out;
    float* fixedR = out + (size_t)NN * OUTD;       // F_input -> fixed_term
    float* Breg   = out + 2 * (size_t)NN * OUTD;   // B

    char* wsb = (char*)d_ws;

    // tier-A layout
    size_t oOvfCnt = 2 * (size_t)NN * 4;                 // after cntA,cntD
    size_t oListA  = oOvfCnt + 16;
    size_t oListD  = oListA + (size_t)NN * CAPA * 8;
    size_t oBA     = oListD + (size_t)NN * CAPD * 8;
    size_t oPack   = oBA + (size_t)NN * RK * 4;
    size_t oOvf    = oPack + (size_t)NN * DD * 4;
    int    ovfCap  = E + ED;
    size_t needA   = oOvf + (size_t)ovfCap * 16;
    // tier-B layout (round-1)
    size_t bListA  = 2 * (size_t)NN * 4;
    size_t bListD  = bListA + (size_t)NN * CAPA * 8;
    size_t bBA     = bListD + (size_t)NN * CAPD * 8;
    size_t needB   = bBA + (size_t)NN * RK * 4;

    if (ws_size >= needA) {
        int*   cntA   = (int*)wsb;
        int*   cntD   = cntA + NN;
        int*   ovfCnt = (int*)(wsb + oOvfCnt);
        uint2* listA  = (uint2*)(wsb + oListA);
        uint2* listD  = (uint2*)(wsb + oListD);
        float* BA     = (float*)(wsb + oBA);
        uint4* packed = (uint4*)(wsb + oPack);
        int4*  ovf    = (int4*)(wsb + oOvf);

        hipMemsetAsync(cntA, 0, oOvfCnt + 16, stream);  // cnts + ovfCnt
        int n4 = NN * (DD / 4);
        k_pack<<<(n4 + 255) / 256, 256, 0, stream>>>(
            (const float4*)feat, (const float4*)dfeat, packed, n4);
        k_build2<<<(E + 255) / 256, 256, 0, stream>>>(
            arow, acol, aval, E, CAPA, cntA, listA, ovfCnt, ovf, ovfCap, 0);
        k_build2<<<(ED + 255) / 256, 256, 0, stream>>>(
            drow, dcol, dval, ED, CAPD, cntD, listD, ovfCnt, ovf, ovfCap, 1);
        k_spmm2<<<(NN * 64 + 255) / 256, 256, 0, stream>>>(
            cntA, listA, cntD, listD, packed, fixedR, Breg, loraA, BA);
        k_fixup<<<128, 256, 0, stream>>>(
            ovfCnt, ovf, ovfCap, feat, dfeat, fixedR, Breg, loraA, BA);
        k_gemm<<<NN / GR, 128, 0, stream>>>(fixedR, W, BA, loraB, newZ);
    } else if (ws_size >= needB) {
        int*   cntA  = (int*)wsb;
        int*   cntD  = cntA + NN;
        uint2* listA = (uint2*)(wsb + bListA);
        uint2* listD = (uint2*)(wsb + bListD);
        float* BA    = (float*)(wsb + bBA);

        hipMemsetAsync(fixedR, 0, (size_t)NN * DD * 4, stream);
        hipMemsetAsync(Breg,   0, (size_t)NN * DD * 4, stream);
        hipMemsetAsync(cntA, 0, 2 * (size_t)NN * 4, stream);
        k_build<<<(E + 255) / 256, 256, 0, stream>>>(
            arow, acol, aval, E, CAPA, cntA, listA, feat, dfeat, Breg, fixedR, 0);
        k_build<<<(ED + 255) / 256, 256, 0, stream>>>(
            drow, dcol, dval, ED, CAPD, cntD, listD, feat, dfeat, Breg, fixedR, 1);
        k_spmm<<<(NN * 64 + 255) / 256, 256, 0, stream>>>(
            cntA, listA, cntD, listD, feat, dfeat, Breg, fixedR);
        k_bba<<<(NN * 64 + 255) / 256, 256, 0, stream>>>(fixedR, Breg, loraA, BA);
        k_gemm<<<NN / GR, 128, 0, stream>>>(fixedR, W, BA, loraB, newZ);
    } else {
        float* BA = (float*)wsb;
        hipMemsetAsync(fixedR, 0, (size_t)NN * DD * 4, stream);
        hipMemsetAsync(Breg,   0, (size_t)NN * DD * 4, stream);
        k_scatter_adj<<<(int)(((size_t)E * 64 + 255) / 256), 256, 0, stream>>>(
            arow, acol, aval, E, feat, dfeat, Breg, fixedR);
        k_scatter_delta<<<(int)(((size_t)ED * 64 + 255) / 256), 256, 0, stream>>>(
            drow, dcol, dval, ED, feat, dfeat, fixedR);
        k_bba<<<(NN * 64 + 255) / 256, 256, 0, stream>>>(fixedR, Breg, loraA, BA);
        k_gemm<<<NN / GR, 128, 0, stream>>>(fixedR, W, BA, loraB, newZ);
    }
}

// Round 7
// 531.776 us; speedup vs baseline: 1.4109x; 1.0970x over previous
//
#include <hip/hip_runtime.h>

#define NN 50000
#define DD 256
#define OUTD 256
#define RK 8
#define CAPA 64
#define CAPD 16
#define SCALING 2.0f
#define GR 16

typedef unsigned int u32;
typedef __attribute__((ext_vector_type(8))) short short8;
typedef __attribute__((ext_vector_type(4))) float f32x4;

__device__ __forceinline__ u32 pack_bf16pair(float lo, float hi) {
    u32 a = __float_as_uint(lo);
    u32 b = __float_as_uint(hi);
    u32 al = (a + 0x7fffu + ((a >> 16) & 1u)) >> 16;          // rne bf16 of lo
    u32 bh = (b + 0x7fffu + ((b >> 16) & 1u)) & 0xffff0000u;  // rne bf16 of hi, in place
    return al | bh;
}

__device__ __forceinline__ unsigned short bf16rne(float x) {
    u32 u = __float_as_uint(x);
    return (unsigned short)((u + 0x7fffu + ((u >> 16) & 1u)) >> 16);
}

// ---------------------------------------------------------------------------
// Pack (bf16(feat), bf16(dfeat)) into one u32 per element.
// ---------------------------------------------------------------------------
__global__ __launch_bounds__(256) void k_pack(
    const float4* __restrict__ f, const float4* __restrict__ df,
    uint4* __restrict__ p, int n4)
{
    int i = blockIdx.x * 256 + threadIdx.x;
    if (i >= n4) return;
    float4 a = f[i], b = df[i];
    uint4 o;
    o.x = pack_bf16pair(a.x, b.x);
    o.y = pack_bf16pair(a.y, b.y);
    o.z = pack_bf16pair(a.z, b.z);
    o.w = pack_bf16pair(a.w, b.w);
    p[i] = o;
}

// ---------------------------------------------------------------------------
// Wt[n][k] = bf16(W[k][n]); runs AFTER k_spmm2, writing over the dead cnt
// region of ws (cnts are not read by any later kernel; ovfCnt sits past it).
// ---------------------------------------------------------------------------
__global__ __launch_bounds__(256) void k_prepw(
    const float* __restrict__ W, unsigned short* __restrict__ Wt)
{
    int n = blockIdx.x;
    int k = threadIdx.x;
    Wt[(size_t)n * DD + k] = bf16rne(W[(size_t)k * OUTD + n]);
}

// ---------------------------------------------------------------------------
// Build per-row edge lists; overflow goes to a list consumed by k_fixup.
// ---------------------------------------------------------------------------
__global__ __launch_bounds__(256) void k_build2(
    const int* __restrict__ erow, const int* __restrict__ ecol,
    const float* __restrict__ eval, int ne, int cap,
    int* __restrict__ cnt, uint2* __restrict__ list,
    int* __restrict__ ovfCnt, int4* __restrict__ ovf, int ovfCap, int isDelta)
{
    int e = blockIdx.x * 256 + threadIdx.x;
    if (e >= ne) return;
    int r = erow[e];
    int c = ecol[e];
    float v = eval[e];
    int slot = atomicAdd(cnt + r, 1);
    if (slot < cap) {
        list[(size_t)r * cap + slot] = make_uint2((u32)c, __float_as_uint(v));
    } else {
        int o = atomicAdd(ovfCnt, 1);
        if (o < ovfCap) ovf[o] = make_int4(r, c, __float_as_int(v), isDelta);
    }
}

// ---------------------------------------------------------------------------
// Wave-per-row pull SpMM on packed bf16 pairs. Fuses Fin, B, BA = B@lora_A.
// ---------------------------------------------------------------------------
__global__ __launch_bounds__(256) void k_spmm2(
    const int* __restrict__ cntA, const uint2* __restrict__ listA,
    const int* __restrict__ cntD, const uint2* __restrict__ listD,
    const uint4* __restrict__ packed,
    float* __restrict__ Fin, float* __restrict__ Bout,
    const float* __restrict__ loraA, float* __restrict__ BA)
{
    int wid  = (int)((blockIdx.x * 256 + threadIdx.x) >> 6);
    int lane = threadIdx.x & 63;
    if (wid >= NN) return;
    int degA = min(cntA[wid], CAPA);
    int degD = min(cntD[wid], CAPD);
    uint2 myA = make_uint2(0u, 0u);
    if (lane < degA) myA = listA[(size_t)wid * CAPA + lane];
    uint2 myD = make_uint2(0u, 0u);
    if (lane < degD) myD = listD[(size_t)wid * CAPD + lane];

    float4 aF = make_float4(0.f, 0.f, 0.f, 0.f);
    float4 aD = make_float4(0.f, 0.f, 0.f, 0.f);

    for (int e = 0; e < degA; ++e) {
        int   c = __shfl((int)myA.x, e);
        float v = __shfl(__uint_as_float(myA.y), e);
        uint4 w = packed[(size_t)c * 64 + lane];
        float f0 = __uint_as_float(w.x << 16), d0 = __uint_as_float(w.x & 0xffff0000u);
        float f1 = __uint_as_float(w.y << 16), d1 = __uint_as_float(w.y & 0xffff0000u);
        float f2 = __uint_as_float(w.z << 16), d2 = __uint_as_float(w.z & 0xffff0000u);
        float f3 = __uint_as_float(w.w << 16), d3 = __uint_as_float(w.w & 0xffff0000u);
        aF.x = fmaf(v, f0, aF.x); aD.x = fmaf(v, d0, aD.x);
        aF.y = fmaf(v, f1, aF.y); aD.y = fmaf(v, d1, aD.y);
        aF.z = fmaf(v, f2, aF.z); aD.z = fmaf(v, d2, aD.z);
        aF.w = fmaf(v, f3, aF.w); aD.w = fmaf(v, d3, aD.w);
    }
    for (int e = 0; e < degD; ++e) {
        int   c = __shfl((int)myD.x, e);
        float v = __shfl(__uint_as_float(myD.y), e);
        uint4 w = packed[(size_t)c * 64 + lane];
        float f0 = __uint_as_float(w.x << 16), d0 = __uint_as_float(w.x & 0xffff0000u);
        float f1 = __uint_as_float(w.y << 16), d1 = __uint_as_float(w.y & 0xffff0000u);
        float f2 = __uint_as_float(w.z << 16), d2 = __uint_as_float(w.z & 0xffff0000u);
        float f3 = __uint_as_float(w.w << 16), d3 = __uint_as_float(w.w & 0xffff0000u);
        aD.x = fmaf(v, f0 + d0, aD.x);
        aD.y = fmaf(v, f1 + d1, aD.y);
        aD.z = fmaf(v, f2 + d2, aD.z);
        aD.w = fmaf(v, f3 + d3, aD.w);
    }

    // Fin is re-read by k_gemm2 (keep cacheable); Bout is never re-read (NT).
    ((float4*)(Fin + (size_t)wid * DD))[lane] = aD;
    f32x4 b;
    b.x = aF.x + aD.x; b.y = aF.y + aD.y; b.z = aF.z + aD.z; b.w = aF.w + aD.w;
    __builtin_nontemporal_store(b, (f32x4*)(Bout + (size_t)wid * DD) + lane);

    int j0 = lane * 4;
    float pa[RK];
#pragma unroll
    for (int p = 0; p < RK; ++p) {
        pa[p] = b.x * loraA[(size_t)(j0 + 0) * RK + p]
              + b.y * loraA[(size_t)(j0 + 1) * RK + p]
              + b.z * loraA[(size_t)(j0 + 2) * RK + p]
              + b.w * loraA[(size_t)(j0 + 3) * RK + p];
    }
#pragma unroll
    for (int off = 32; off; off >>= 1) {
#pragma unroll
        for (int p = 0; p < RK; ++p) pa[p] += __shfl_xor(pa[p], off);
    }
    if (lane == 0) {
#pragma unroll
        for (int p = 0; p < RK; ++p) BA[(size_t)wid * RK + p] = pa[p];
    }
}

// ---------------------------------------------------------------------------
// Patch Fin/B/BA for overflow edges (≈never runs; runs before k_gemm2 so the
// GEMM sees patched Fin/BA).
// ---------------------------------------------------------------------------
__global__ __launch_bounds__(256) void k_fixup(
    const int* __restrict__ ovfCnt, const int4* __restrict__ ovf, int ovfCap,
    const float* __restrict__ feat, const float* __restrict__ dfeat,
    float* Fin, float* Bout, const float* __restrict__ loraA, float* BA)
{
    int waveId = (int)((blockIdx.x * 256 + threadIdx.x) >> 6);
    int nWaves = (int)(gridDim.x * 256 / 64);
    int lane = threadIdx.x & 63;
    int n = min(*ovfCnt, ovfCap);
    for (int i = waveId; i < n; i += nWaves) {
        int4 t = ovf[i];
        int r = t.x, c = t.y, isD = t.w;
        float v = __int_as_float(t.z);
        float4 f  = ((const float4*)(feat  + (size_t)c * DD))[lane];
        float4 df = ((const float4*)(dfeat + (size_t)c * DD))[lane];
        float4 dF, dB;
        if (isD) {
            dF = make_float4(v * (f.x + df.x), v * (f.y + df.y), v * (f.z + df.z), v * (f.w + df.w));
            dB = dF;
        } else {
            dF = make_float4(v * df.x, v * df.y, v * df.z, v * df.w);
            dB = make_float4(fmaf(v, f.x, dF.x), fmaf(v, f.y, dF.y), fmaf(v, f.z, dF.z), fmaf(v, f.w, dF.w));
        }
        float* pF = Fin  + (size_t)r * DD + lane * 4;
        float* pB = Bout + (size_t)r * DD + lane * 4;
        atomicAdd(pF + 0, dF.x); atomicAdd(pF + 1, dF.y);
        atomicAdd(pF + 2, dF.z); atomicAdd(pF + 3, dF.w);
        atomicAdd(pB + 0, dB.x); atomicAdd(pB + 1, dB.y);
        atomicAdd(pB + 2, dB.z); atomicAdd(pB + 3, dB.w);
        int j0 = lane * 4;
        float pa[RK];
#pragma unroll
        for (int p = 0; p < RK; ++p) {
            pa[p] = dB.x * loraA[(size_t)(j0 + 0) * RK + p]
                  + dB.y * loraA[(size_t)(j0 + 1) * RK + p]
                  + dB.z * loraA[(size_t)(j0 + 2) * RK + p]
                  + dB.w * loraA[(size_t)(j0 + 3) * RK + p];
        }
#pragma unroll
        for (int off = 32; off; off >>= 1) {
#pragma unroll
            for (int p = 0; p < RK; ++p) pa[p] += __shfl_xor(pa[p], off);
        }
        if (lane == 0) {
#pragma unroll
            for (int p = 0; p < RK; ++p) atomicAdd(BA + (size_t)r * RK + p, pa[p]);
        }
    }
}

// ---------------------------------------------------------------------------
// MFMA GEMM: fixed = Fin @ W, newZ = fixed + (BA @ lora_B)*SCALING.
// Block: 256 threads = 4 waves; 64 rows x 256 cols; wave w owns rows
// w*16..w*16+15, all 256 cols as 16 mfma_f32_16x16x32_bf16 fragments.
// A: lane holds A[l&15][8*(l>>4)+i] (f32->bf16 rne in-reg).
// B: lane holds B[8*(l>>4)+i][l&15] (contiguous in Wt[col][k]).
// D: reg r, lane l -> D[4*(l>>4)+r][l&15]  [guide-verified m89].
// ---------------------------------------------------------------------------
__global__ __launch_bounds__(256) void k_gemm2(
    const float* __restrict__ Fin, const unsigned short* __restrict__ Wt,
    const float* __restrict__ BA, const float* __restrict__ loraB,
    float* __restrict__ fixed, float* __restrict__ zOut)
{
    __shared__ float lb[RK][OUTD];   // lora_B * SCALING
    __shared__ float baL[64][RK];    // BA rows of this block
    int t = threadIdx.x;
    int row0 = blockIdx.x * 64;

#pragma unroll
    for (int i = 0; i < 8; ++i) {
        int idx = i * 256 + t;
        lb[idx >> 8][idx & 255] = loraB[idx] * SCALING;
    }
    if (t < 128) {
        int r = t >> 1, h = t & 1;
        int grow = row0 + r;
        float4 v = make_float4(0.f, 0.f, 0.f, 0.f);
        if (grow < NN) v = ((const float4*)(BA + (size_t)grow * RK))[h];
        ((float4*)&baL[r][0])[h] = v;
    }
    __syncthreads();

    int wave = t >> 6, lane = t & 63;
    int wr0 = wave * 16;
    int grow0 = row0 + wr0;
    if (grow0 >= NN) return;   // partial last block: only some waves active
    int arow = grow0 + (lane & 15);
    int kg = lane >> 4;

    f32x4 acc[16];
#pragma unroll
    for (int f = 0; f < 16; ++f) acc[f] = (f32x4){0.f, 0.f, 0.f, 0.f};

#pragma unroll
    for (int s = 0; s < 8; ++s) {
        const float* pA = Fin + (size_t)arow * DD + s * 32 + kg * 8;
        float4 a0 = *(const float4*)pA;
        float4 a1 = *(const float4*)(pA + 4);
        short8 av;
        av[0] = (short)bf16rne(a0.x); av[1] = (short)bf16rne(a0.y);
        av[2] = (short)bf16rne(a0.z); av[3] = (short)bf16rne(a0.w);
        av[4] = (short)bf16rne(a1.x); av[5] = (short)bf16rne(a1.y);
        av[6] = (short)bf16rne(a1.z); av[7] = (short)bf16rne(a1.w);
        const unsigned short* pB0 = Wt + (size_t)(lane & 15) * DD + s * 32 + kg * 8;
#pragma unroll
        for (int f = 0; f < 16; ++f) {
            short8 bv = *(const short8*)(pB0 + (size_t)f * 16 * DD);
            acc[f] = __builtin_amdgcn_mfma_f32_16x16x32_bf16(av, bv, acc[f], 0, 0, 0);
        }
    }

    float bav[4][RK];
#pragma unroll
    for (int r = 0; r < 4; ++r)
#pragma unroll
        for (int p = 0; p < RK; ++p)
            bav[r][p] = baL[wr0 + 4 * (lane >> 4) + r][p];

#pragma unroll
    for (int f = 0; f < 16; ++f) {
        int col = f * 16 + (lane & 15);
#pragma unroll
        for (int r = 0; r < 4; ++r) {
            int grow = grow0 + 4 * (lane >> 4) + r;
            size_t off = (size_t)grow * OUTD + col;
            float fx = acc[f][r];
            float z = fx;
#pragma unroll
            for (int p = 0; p < RK; ++p) z = fmaf(bav[r][p], lb[p][col], z);
            __builtin_nontemporal_store(fx, fixed + off);
            __builtin_nontemporal_store(z, zOut + off);
        }
    }
}

// ===========================================================================
// Fallback tier-B kernels (used only if ws is too small). Correct always.
// ===========================================================================
__global__ __launch_bounds__(256) void k_build(
    const int* __restrict__ erow, const int* __restrict__ ecol,
    const float* __restrict__ eval, int ne, int cap,
    int* __restrict__ cnt, uint2* __restrict__ list,
    const float* __restrict__ feat, const float* __restrict__ dfeat,
    float* acc0, float* acc1, int isDelta)
{
    int e = blockIdx.x * 256 + threadIdx.x;
    if (e >= ne) return;
    int r = erow[e];
    int c = ecol[e];
    float v = eval[e];
    int slot = atomicAdd(cnt + r, 1);
    if (slot < cap) {
        list[(size_t)r * cap + slot] = make_uint2((u32)c, __float_as_uint(v));
    } else {
        const float* f  = feat  + (size_t)c * DD;
        const float* df = dfeat + (size_t)c * DD;
        float* a0 = acc0 + (size_t)r * DD;
        float* a1 = acc1 + (size_t)r * DD;
        if (isDelta) {
            for (int i = 0; i < DD; ++i) atomicAdd(a1 + i, v * (f[i] + df[i]));
        } else {
            for (int i = 0; i < DD; ++i) {
                atomicAdd(a0 + i, v * f[i]);
                atomicAdd(a1 + i, v * df[i]);
            }
        }
    }
}

__global__ __launch_bounds__(256) void k_spmm(
    const int* __restrict__ cntA, const uint2* __restrict__ listA,
    const int* __restrict__ cntD, const uint2* __restrict__ listD,
    const float* __restrict__ feat, const float* __restrict__ dfeat,
    float* accAdjF, float* accFin)
{
    int wid  = (int)((blockIdx.x * 256 + threadIdx.x) >> 6);
    int lane = threadIdx.x & 63;
    if (wid >= NN) return;
    int degA = min(cntA[wid], CAPA);
    int degD = min(cntD[wid], CAPD);
    uint2 myA = listA[(size_t)wid * CAPA + lane];
    uint2 myD = make_uint2(0u, 0u);
    if (lane < CAPD) myD = listD[(size_t)wid * CAPD + lane];
    float4 aF = make_float4(0.f, 0.f, 0.f, 0.f);
    float4 aD = make_float4(0.f, 0.f, 0.f, 0.f);
    for (int e = 0; e < degA; ++e) {
        int   c = __shfl((int)myA.x, e);
        float v = __shfl(__uint_as_float(myA.y), e);
        float4 f  = ((const float4*)(feat  + (size_t)c * DD))[lane];
        float4 df = ((const float4*)(dfeat + (size_t)c * DD))[lane];
        aF.x = fmaf(v, f.x, aF.x);  aF.y = fmaf(v, f.y, aF.y);
        aF.z = fmaf(v, f.z, aF.z);  aF.w = fmaf(v, f.w, aF.w);
        aD.x = fmaf(v, df.x, aD.x); aD.y = fmaf(v, df.y, aD.y);
        aD.z = fmaf(v, df.z, aD.z); aD.w = fmaf(v, df.w, aD.w);
    }
    for (int e = 0; e < degD; ++e) {
        int   c = __shfl((int)myD.x, e);
        float v = __shfl(__uint_as_float(myD.y), e);
        float4 f  = ((const float4*)(feat  + (size_t)c * DD))[lane];
        float4 df = ((const float4*)(dfeat + (size_t)c * DD))[lane];
        aD.x = fmaf(v, f.x + df.x, aD.x); aD.y = fmaf(v, f.y + df.y, aD.y);
        aD.z = fmaf(v, f.z + df.z, aD.z); aD.w = fmaf(v, f.w + df.w, aD.w);
    }
    float4* p0 = (float4*)(accAdjF + (size_t)wid * DD) + lane;
    float4 t0 = *p0;
    t0.x += aF.x; t0.y += aF.y; t0.z += aF.z; t0.w += aF.w;
    *p0 = t0;
    float4* p1 = (float4*)(accFin + (size_t)wid * DD) + lane;
    float4 t1 = *p1;
    t1.x += aD.x; t1.y += aD.y; t1.z += aD.z; t1.w += aD.w;
    *p1 = t1;
}

__global__ __launch_bounds__(256) void k_scatter_adj(
    const int* __restrict__ erow, const int* __restrict__ ecol,
    const float* __restrict__ eval, int ne,
    const float* __restrict__ feat, const float* __restrict__ dfeat,
    float* accAdjF, float* accFin)
{
    int e    = (int)((blockIdx.x * 256 + threadIdx.x) >> 6);
    int lane = threadIdx.x & 63;
    if (e >= ne) return;
    int r = erow[e]; int c = ecol[e]; float v = eval[e];
    float4 f  = ((const float4*)(feat  + (size_t)c * DD))[lane];
    float4 df = ((const float4*)(dfeat + (size_t)c * DD))[lane];
    float* pA = accAdjF + (size_t)r * DD + lane * 4;
    atomicAdd(pA + 0, v * f.x); atomicAdd(pA + 1, v * f.y);
    atomicAdd(pA + 2, v * f.z); atomicAdd(pA + 3, v * f.w);
    float* pF = accFin + (size_t)r * DD + lane * 4;
    atomicAdd(pF + 0, v * df.x); atomicAdd(pF + 1, v * df.y);
    atomicAdd(pF + 2, v * df.z); atomicAdd(pF + 3, v * df.w);
}

__global__ __launch_bounds__(256) void k_scatter_delta(
    const int* __restrict__ erow, const int* __restrict__ ecol,
    const float* __restrict__ eval, int ne,
    const float* __restrict__ feat, const float* __restrict__ dfeat,
    float* accFin)
{
    int e    = (int)((blockIdx.x * 256 + threadIdx.x) >> 6);
    int lane = threadIdx.x & 63;
    if (e >= ne) return;
    int r = erow[e]; int c = ecol[e]; float v = eval[e];
    float4 f  = ((const float4*)(feat  + (size_t)c * DD))[lane];
    float4 df = ((const float4*)(dfeat + (size_t)c * DD))[lane];
    float* pF = accFin + (size_t)r * DD + lane * 4;
    atomicAdd(pF + 0, v * (f.x + df.x)); atomicAdd(pF + 1, v * (f.y + df.y));
    atomicAdd(pF + 2, v * (f.z + df.z)); atomicAdd(pF + 3, v * (f.w + df.w));
}

__global__ __launch_bounds__(256) void k_bba(
    const float* __restrict__ accFin, float* bio,
    const float* __restrict__ loraA, float* __restrict__ BA)
{
    int wid  = (int)((blockIdx.x * 256 + threadIdx.x) >> 6);
    int lane = threadIdx.x & 63;
    if (wid >= NN) return;
    float4 fin = ((const float4*)(accFin + (size_t)wid * DD))[lane];
    float4* pb = (float4*)(bio + (size_t)wid * DD) + lane;
    float4 b = *pb;
    b.x += fin.x; b.y += fin.y; b.z += fin.z; b.w += fin.w;
    *pb = b;
    int j0 = lane * 4;
    float pa[RK];
#pragma unroll
    for (int p = 0; p < RK; ++p) {
        pa[p] = b.x * loraA[(size_t)(j0 + 0) * RK + p]
              + b.y * loraA[(size_t)(j0 + 1) * RK + p]
              + b.z * loraA[(size_t)(j0 + 2) * RK + p]
              + b.w * loraA[(size_t)(j0 + 3) * RK + p];
    }
#pragma unroll
    for (int off = 32; off; off >>= 1) {
#pragma unroll
        for (int p = 0; p < RK; ++p) pa[p] += __shfl_xor(pa[p], off);
    }
    if (lane == 0) {
#pragma unroll
        for (int p = 0; p < RK; ++p) BA[(size_t)wid * RK + p] = pa[p];
    }
}

__global__ __launch_bounds__(128) void k_gemm(
    float* finIO,
    const float* __restrict__ W,
    const float* __restrict__ BA,
    const float* __restrict__ loraB,
    float* __restrict__ zOut)
{
    __shared__ float fin[GR][DD + 4];
    __shared__ float lb[RK][OUTD];
    __shared__ float ba[GR][RK];
    int t = threadIdx.x;
    int row0 = blockIdx.x * GR;

#pragma unroll
    for (int i = 0; i < 8; ++i) {
        int idx = i * 128 + t;
        int r = idx >> 6, p = idx & 63;
        float4 v = ((const float4*)(finIO + (size_t)(row0 + r) * DD))[p];
        *(float4*)&fin[r][p * 4] = v;
    }
#pragma unroll
    for (int i = 0; i < 16; ++i) {
        int idx = i * 128 + t;
        lb[idx >> 8][idx & 255] = loraB[idx] * SCALING;
    }
    ba[t >> 3][t & 7] = BA[(size_t)row0 * RK + t];
    __syncthreads();

    int c0 = t, c1 = t + 128;
    float acc0[GR], acc1[GR];
#pragma unroll
    for (int r = 0; r < GR; ++r) { acc0[r] = 0.f; acc1[r] = 0.f; }

    for (int k = 0; k < DD; k += 4) {
        const float* wk = W + (size_t)k * OUTD;
        float w00 = wk[c0], w01 = wk[OUTD + c0], w02 = wk[2 * OUTD + c0], w03 = wk[3 * OUTD + c0];
        float w10 = wk[c1], w11 = wk[OUTD + c1], w12 = wk[2 * OUTD + c1], w13 = wk[3 * OUTD + c1];
#pragma unroll
        for (int r = 0; r < GR; ++r) {
            float4 f = *(const float4*)&fin[r][k];
            acc0[r] += f.x * w00 + f.y * w01 + f.z * w02 + f.w * w03;
            acc1[r] += f.x * w10 + f.y * w11 + f.z * w12 + f.w * w13;
        }
    }

#pragma unroll
    for (int r = 0; r < GR; ++r) {
        float z0 = acc0[r], z1 = acc1[r];
#pragma unroll
        for (int p = 0; p < RK; ++p) {
            float bv = ba[r][p];
            z0 = fmaf(bv, lb[p][c0], z0);
            z1 = fmaf(bv, lb[p][c1], z1);
        }
        size_t off = (size_t)(row0 + r) * OUTD;
        finIO[off + c0] = acc0[r];
        finIO[off + c1] = acc1[r];
        zOut[off + c0]  = z0;
        zOut[off + c1]  = z1;
    }
}

// ---------------------------------------------------------------------------
extern "C" void kernel_launch(void* const* d_in, const int* in_sizes, int n_in,
                              void* d_out, int out_size, void* d_ws, size_t ws_size,
                              hipStream_t stream)
{
    const float* feat  = (const float*)d_in[0];
    const float* dfeat = (const float*)d_in[1];
    const int*   arow  = (const int*)d_in[2];
    const int*   acol  = (const int*)d_in[3];
    const float* aval  = (const float*)d_in[4];
    const int*   drow  = (const int*)d_in[5];
    const int*   dcol  = (const int*)d_in[6];
    const float* dval  = (const float*)d_in[7];
    const float* W     = (const float*)d_in[8];
    const float* loraA = (const float*)d_in[10];
    const float* loraB = (const float*)d_in[11];
    int E  = in_sizes[2];
    int ED = in_sizes[5];

    float* out    = (float*)d_out;
    float* newZ   = out;
    float* fixedR = out + (size_t)NN * OUTD;       // F_input -> fixed_term
    float* Breg   = out + 2 * (size_t)NN * OUTD;   // B

    char* wsb = (char*)d_ws;

    // tier-A layout (Wt aliases dead cnt region after k_spmm2)
    size_t oOvfCnt = 2 * (size_t)NN * 4;                 // after cntA,cntD
    size_t oListA  = oOvfCnt + 16;
    size_t oListD  = oListA + (size_t)NN * CAPA * 8;
    size_t oBA     = oListD + (size_t)NN * CAPD * 8;
    size_t oPack   = oBA + (size_t)NN * RK * 4;
    size_t oOvf    = oPack + (size_t)NN * DD * 4;
    int    ovfCap  = E + ED;
    size_t needA   = oOvf + (size_t)ovfCap * 16;
    // tier-B layout
    size_t bListA  = 2 * (size_t)NN * 4;
    size_t bListD  = bListA + (size_t)NN * CAPA * 8;
    size_t bBA     = bListD + (size_t)NN * CAPD * 8;
    size_t needB   = bBA + (size_t)NN * RK * 4;

    if (ws_size >= needA) {
        int*   cntA   = (int*)wsb;
        int*   cntD   = cntA + NN;
        int*   ovfCnt = (int*)(wsb + oOvfCnt);
        uint2* listA  = (uint2*)(wsb + oListA);
        uint2* listD  = (uint2*)(wsb + oListD);
        float* BA     = (float*)(wsb + oBA);
        uint4* packed = (uint4*)(wsb + oPack);
        int4*  ovf    = (int4*)(wsb + oOvf);
        unsigned short* Wt = (unsigned short*)wsb;  // 128 KB over dead cntA/cntD

        (void)hipMemsetAsync(cntA, 0, oOvfCnt + 16, stream);  // cnts + ovfCnt
        int n4 = NN * (DD / 4);
        k_pack<<<(n4 + 255) / 256, 256, 0, stream>>>(
            (const float4*)feat, (const float4*)dfeat, packed, n4);
        k_build2<<<(E + 255) / 256, 256, 0, stream>>>(
            arow, acol, aval, E, CAPA, cntA, listA, ovfCnt, ovf, ovfCap, 0);
        k_build2<<<(ED + 255) / 256, 256, 0, stream>>>(
            drow, dcol, dval, ED, CAPD, cntD, listD, ovfCnt, ovf, ovfCap, 1);
        k_spmm2<<<(NN * 64 + 255) / 256, 256, 0, stream>>>(
            cntA, listA, cntD, listD, packed, fixedR, Breg, loraA, BA);
        k_prepw<<<OUTD, DD, 0, stream>>>(W, Wt);   // cnts dead from here on
        k_fixup<<<128, 256, 0, stream>>>(
            ovfCnt, ovf, ovfCap, feat, dfeat, fixedR, Breg, loraA, BA);
        k_gemm2<<<(NN + 63) / 64, 256, 0, stream>>>(
            fixedR, Wt, BA, loraB, fixedR, newZ);
    } else if (ws_size >= needB) {
        int*   cntA  = (int*)wsb;
        int*   cntD  = cntA + NN;
        uint2* listA = (uint2*)(wsb + bListA);
        uint2* listD = (uint2*)(wsb + bListD);
        float* BA    = (float*)(wsb + bBA);

        (void)hipMemsetAsync(fixedR, 0, (size_t)NN * DD * 4, stream);
        (void)hipMemsetAsync(Breg,   0, (size_t)NN * DD * 4, stream);
        (void)hipMemsetAsync(cntA, 0, 2 * (size_t)NN * 4, stream);
        k_build<<<(E + 255) / 256, 256, 0, stream>>>(
            arow, acol, aval, E, CAPA, cntA, listA, feat, dfeat, Breg, fixedR, 0);
        k_build<<<(ED + 255) / 256, 256, 0, stream>>>(
            drow, dcol, dval, ED, CAPD, cntD, listD, feat, dfeat, Breg, fixedR, 1);
        k_spmm<<<(NN * 64 + 255) / 256, 256, 0, stream>>>(
            cntA, listA, cntD, listD, feat, dfeat, Breg, fixedR);
        k_bba<<<(NN * 64 + 255) / 256, 256, 0, stream>>>(fixedR, Breg, loraA, BA);
        k_gemm<<<NN / GR, 128, 0, stream>>>(fixedR, W, BA, loraB, newZ);
    } else {
        float* BA = (float*)wsb;
        (void)hipMemsetAsync(fixedR, 0, (size_t)NN * DD * 4, stream);
        (void)hipMemsetAsync(Breg,   0, (size_t)NN * DD * 4, stream);
        k_scatter_adj<<<(int)(((size_t)E * 64 + 255) / 256), 256, 0, stream>>>(
            arow, acol, aval, E, feat, dfeat, Breg, fixedR);
        k_scatter_delta<<<(int)(((size_t)ED * 64 + 255) / 256), 256, 0, stream>>>(
            drow, dcol, dval, ED, feat, dfeat, fixedR);
        k_bba<<<(NN * 64 + 255) / 256, 256, 0, stream>>>(fixedR, Breg, loraA, BA);
        k_gemm<<<NN / GR, 128, 0, stream>>>(fixedR, W, BA, loraB, newZ);
    }
}